// Round 6
// baseline (5818.818 us; speedup 1.0000x reference)
//
#include <hip/hip_runtime.h>

typedef __attribute__((ext_vector_type(8))) short short8;
typedef __attribute__((ext_vector_type(4))) float f32x4;

__device__ __forceinline__ float bf2f(ushort u) {
  union { unsigned int i; float f; } x; x.i = ((unsigned int)u) << 16; return x.f;
}
__device__ __forceinline__ ushort f2bf(float f) {
  union { float f; unsigned int i; } x; x.f = f;
  unsigned int i = x.i + 0x7fffu + ((x.i >> 16) & 1u);
  return (ushort)(i >> 16);
}
__device__ __forceinline__ float blo(unsigned int u) {
  union { unsigned int i; float f; } x; x.i = u << 16; return x.f;
}
__device__ __forceinline__ float bhi(unsigned int u) {
  union { unsigned int i; float f; } x; x.i = u & 0xffff0000u; return x.f;
}
__device__ __forceinline__ float fast_tanh(float x) {
  x = fminf(fmaxf(x, -15.f), 15.f);
  float e = __expf(2.f * x);
  return __fdividef(e - 1.f, e + 1.f);
}
__device__ __forceinline__ float sigm(float x) { return 1.f / (1.f + __expf(-x)); }
__device__ __forceinline__ void st_agent(float* p, float v) {
  __hip_atomic_store(p, v, __ATOMIC_RELAXED, __HIP_MEMORY_SCOPE_AGENT);
}
__device__ __forceinline__ float ld_agent(const float* p) {
  return __hip_atomic_load(p, __ATOMIC_RELAXED, __HIP_MEMORY_SCOPE_AGENT);
}

// -------- transpose fp32 -> bf16, out[c][r] = bf16(in[r][c]) --------
__global__ void transpose_f2b(const float* __restrict__ in, ushort* __restrict__ out,
                              int R, int C) {
  __shared__ ushort tile[32][33];
  int c0 = blockIdx.x * 32, r0 = blockIdx.y * 32;
  int tx = threadIdx.x, ty = threadIdx.y;  // block (32,8)
  for (int i = 0; i < 32; i += 8) {
    int r = r0 + ty + i, c = c0 + tx;
    if (r < R && c < C) tile[ty + i][tx] = f2bf(in[(size_t)r * C + c]);
  }
  __syncthreads();
  for (int i = 0; i < 32; i += 8) {
    int c = c0 + ty + i, r = r0 + tx;
    if (r < R && c < C) out[(size_t)c * R + r] = tile[tx][ty + i];
  }
}

// -------- gather embedded tokens (fp32 emb -> bf16): embA[t*128+b][:] --------
__global__ void embed_gather(const int* __restrict__ target, const float* __restrict__ emb,
                             ushort* __restrict__ embA) {
  int m = blockIdx.x;            // 0..6015
  int t = m >> 7, b = m & 127;
  int tok = (t == 0) ? 1 : target[b * 48 + t];
  embA[(size_t)m * 256 + threadIdx.x] = f2bf(emb[(size_t)tok * 256 + threadIdx.x]);
}

// ---------------- 128x128 LDS-staged MFMA GEMM ----------------
// C = act(A[M,K] @ B^T + bias), B rows at BT + row*bstride (k-contiguous).
// flags: 1=relu, 2=store fp32, 4=remap rows m=t*128+b -> out row b*47+t, 8=A is fp32
__global__ __launch_bounds__(256) void gemm128(
    const void* __restrict__ Ap, const ushort* __restrict__ BT,
    const float* __restrict__ bias, void* __restrict__ Cout,
    int M, int N, int K, int NrowsB, int bstride, int flags) {
  __shared__ ushort lA[128 * 32];
  __shared__ ushort lB[128 * 32];
  int tid = threadIdx.x;
  int wave = tid >> 6, lane = tid & 63;
  int q = lane >> 4, l16 = lane & 15;
  int wr = wave >> 1, wc = wave & 1;
  int m0 = blockIdx.y * 128, n0 = blockIdx.x * 128;
  f32x4 acc[4][4];
#pragma unroll
  for (int i = 0; i < 4; ++i)
#pragma unroll
    for (int j = 0; j < 4; ++j) acc[i][j] = (f32x4){0.f, 0.f, 0.f, 0.f};
  int r0 = tid >> 2, cc0 = (tid & 3) * 8;
  int r1 = r0 + 64, cc1 = cc0;
  int rb0 = n0 + r0; if (rb0 >= NrowsB) rb0 = NrowsB - 1;
  int rb1 = n0 + r1; if (rb1 >= NrowsB) rb1 = NrowsB - 1;
  for (int k = 0; k < K; k += 32) {
    short8 va0, va1, vb0, vb1;
    if (flags & 8) {
      const float* s0 = (const float*)Ap + (size_t)(m0 + r0) * K + k + cc0;
      const float* s1 = (const float*)Ap + (size_t)(m0 + r1) * K + k + cc1;
      short8 t0, t1;
#pragma unroll
      for (int e = 0; e < 8; ++e) { t0[e] = (short)f2bf(s0[e]); t1[e] = (short)f2bf(s1[e]); }
      va0 = t0; va1 = t1;
    } else {
      va0 = *(const short8*)((const ushort*)Ap + (size_t)(m0 + r0) * K + k + cc0);
      va1 = *(const short8*)((const ushort*)Ap + (size_t)(m0 + r1) * K + k + cc1);
    }
    vb0 = *(const short8*)(BT + (size_t)rb0 * bstride + k + cc0);
    vb1 = *(const short8*)(BT + (size_t)rb1 * bstride + k + cc1);
    __syncthreads();
    *(short8*)&lA[r0 * 32 + cc0] = va0;
    *(short8*)&lA[r1 * 32 + cc1] = va1;
    *(short8*)&lB[r0 * 32 + cc0] = vb0;
    *(short8*)&lB[r1 * 32 + cc1] = vb1;
    __syncthreads();
    short8 af[4], bfr[4];
#pragma unroll
    for (int i = 0; i < 4; ++i)
      af[i] = *(const short8*)&lA[(wr * 64 + i * 16 + l16) * 32 + q * 8];
#pragma unroll
    for (int j = 0; j < 4; ++j)
      bfr[j] = *(const short8*)&lB[(wc * 64 + j * 16 + l16) * 32 + q * 8];
#pragma unroll
    for (int i = 0; i < 4; ++i)
#pragma unroll
      for (int j = 0; j < 4; ++j)
        acc[i][j] = __builtin_amdgcn_mfma_f32_16x16x32_bf16(af[i], bfr[j], acc[i][j], 0, 0, 0);
  }
#pragma unroll
  for (int i = 0; i < 4; ++i)
#pragma unroll
    for (int j = 0; j < 4; ++j)
#pragma unroll
      for (int r = 0; r < 4; ++r) {
        int gr = m0 + wr * 64 + i * 16 + q * 4 + r;  // D row = quad*4 + reg [m89/m91]
        int gc = n0 + wc * 64 + j * 16 + l16;        // D col = lane&15
        if (gc >= N) continue;
        float v = acc[i][j][r];
        if (bias) v += bias[gc];
        if (flags & 1) v = fmaxf(v, 0.f);
        size_t orow = (size_t)gr;
        if (flags & 4) { int t = gr >> 7, bb = gr & 127; orow = (size_t)bb * 47 + t; }
        if (flags & 2) ((float*)Cout)[orow * (size_t)N + gc] = v;
        else ((ushort*)Cout)[orow * (size_t)N + gc] = f2bf(v);
      }
}

// ---------------- persistent pair loop: 2 blocks per batch row, u-split ----------------
// Block (b, h): handles u in [h*256, h*256+256) for hw2/scores/gates.
// W2 slice lives in 128 VGPRs (loaded once); featK slice (768x64) lives in LDS (once);
// featW1 slice in 8 VGPRs. In-loop global traffic ~4KB/block/step.
// Partner exchange (same-XCD pair bid^8): partial scores + state half, via agent-scope
// atomics + flag sync. Cooperative launch guarantees all 256 blocks co-resident.
__global__ __launch_bounds__(512, 2) void row_pair(
    const ushort* __restrict__ featW1,   // (8192,512) bf16
    const ushort* __restrict__ W2T,      // (512,512) bf16, row u = col u of W2
    const float* __restrict__ b2,        // (512)
    const float* __restrict__ V,         // (512)
    const float* __restrict__ bV,        // (1)
    const ushort* __restrict__ featK,    // (8192,1536) bf16 = features @ gru_k[0:256]
    const ushort* __restrict__ xE,       // (6016,1536) bf16 = embA @ gru_k[256:512]
    const float* __restrict__ grub0,     // (1536)
    const float* __restrict__ grub1,     // (1536)
    ushort* __restrict__ states,         // (48,128,512) bf16; rows 1..47 written
    float* __restrict__ stateF,          // (2,128,512) f32 exchange, parity-buffered
    float* __restrict__ scG,             // (128,2,64) f32 partial scores
    int* __restrict__ flagA,             // (256) score-ready flags (pre-zeroed)
    int* __restrict__ flagB) {           // (256) state-ready flags (pre-zeroed)
  int bid = blockIdx.x, tid = threadIdx.x;
  int h = (bid >> 3) & 1;                       // partner = bid^8 -> same XCD (mod-8 rr)
  int b = (bid & 7) * 16 + (bid >> 4);          // bijective over (bid&7, bid>>4)
  int ph = 1 - h;
  int fown = b * 2 + h, fpar = b * 2 + ph;

  __shared__ __align__(16) ushort fkT[768][64]; // fkT[j][l]: local gate-col j, region l
  __shared__ __align__(16) float stf_p[544];    // state, padded: val k at k + (k>>6)*4
  __shared__ float hw2p[264], Vvp[264];         // padded: val u at u + (u>>5)
  __shared__ float scOwn[64], attnw[64];
  __shared__ float xbuf[768];

  // ---- one-time init ----
  if (tid < 256) Vvp[tid + (tid >> 5)] = V[h * 256 + tid];
  for (int i = tid; i < 544; i += 512) stf_p[i] = 0.f;  // hidden_0 = 0 (both halves)
  {  // featK slice -> LDS, coalesced reads (lane = col)
    int w = tid >> 6, lane = tid & 63;
    for (int l = w; l < 64; l += 8) {
      const ushort* src = featK + (size_t)(b * 64 + l) * 1536;
      for (int c = lane; c < 768; c += 64) {
        int gc = (c >> 8) * 512 + h * 256 + (c & 255);
        fkT[c][l] = src[gc];
      }
    }
  }
  // W2 slice -> 128 VGPRs: rows h*256 + up*4 + i, k-chunk hk*64 + m*8
  int hk = tid & 7, up = tid >> 3;
  uint4 wreg[32];
#pragma unroll
  for (int i = 0; i < 4; ++i)
#pragma unroll
    for (int m = 0; m < 8; ++m)
      wreg[i * 8 + m] = *(const uint4*)(W2T + (size_t)(h * 256 + up * 4 + i) * 512 + hk * 64 + m * 8);
  float b2v0 = b2[h * 256 + up * 4], b2v1 = b2[h * 256 + up * 4 + 1];
  float b2v2 = b2[h * 256 + up * 4 + 2], b2v3 = b2[h * 256 + up * 4 + 3];
  // featW1 slice -> 8 VGPRs: row b*64 + lr, cols h*256 + part*32 .. +32
  int lr = tid >> 3, part = tid & 7;
  uint4 fwreg[4];
#pragma unroll
  for (int i = 0; i < 4; ++i)
    fwreg[i] = *(const uint4*)(featW1 + (size_t)(b * 64 + lr) * 512 + h * 256 + part * 32 + i * 8);
  // gate biases (threads 0..255, unit u = h*256 + tid)
  float g0z = 0, g0r = 0, g0h = 0, g1z = 0, g1r = 0, g1h = 0;
  if (tid < 256) {
    int gu = h * 256 + tid;
    g0z = grub0[gu]; g0r = grub0[512 + gu]; g0h = grub0[1024 + gu];
    g1z = grub1[gu]; g1r = grub1[512 + gu]; g1h = grub1[1024 + gu];
  }
  float bVr = bV[0];
  __syncthreads();

#pragma unroll 1
  for (int t = 0; t < 47; ++t) {
    // prefetch this step's xE values (independent of syncs; consumed in P4)
    const ushort* xerow = xE + (size_t)(t * 128 + b) * 1536;
    ushort xe1 = xerow[(tid >> 8) * 512 + h * 256 + (tid & 255)];
    ushort xe2 = (tid < 256) ? xerow[1024 + h * 256 + tid] : (ushort)0;
    // ---- wait partner state half (t>0), read into stf ----
    if (t > 0) {
      if (tid == 0) {
        while (atomicAdd(&flagB[fpar], 0) < t) __builtin_amdgcn_s_sleep(2);
      }
      __syncthreads();
      __threadfence();
      if (tid < 256) {
        int gu = ph * 256 + tid;
        stf_p[gu + (gu >> 6) * 4] =
            ld_agent(&stateF[(size_t)(t & 1) * 65536 + (size_t)b * 512 + gu]);
      }
    }
    __syncthreads();
    // ---- P1: hw2[u] = state . W2[:,u] + b2[u]; 4 rows x 64k per thread, regs x LDS ----
    {
      float a0 = 0, a1 = 0, a2 = 0, a3 = 0;
      const float* sb = &stf_p[hk * 68];
#pragma unroll
      for (int m = 0; m < 8; ++m) {
        float4 sA = *(const float4*)(sb + m * 8);
        float4 sB = *(const float4*)(sb + m * 8 + 4);
        uint4 w0 = wreg[m], w1 = wreg[8 + m], w2 = wreg[16 + m], w3 = wreg[24 + m];
        a0 += blo(w0.x) * sA.x + bhi(w0.x) * sA.y + blo(w0.y) * sA.z + bhi(w0.y) * sA.w +
              blo(w0.z) * sB.x + bhi(w0.z) * sB.y + blo(w0.w) * sB.z + bhi(w0.w) * sB.w;
        a1 += blo(w1.x) * sA.x + bhi(w1.x) * sA.y + blo(w1.y) * sA.z + bhi(w1.y) * sA.w +
              blo(w1.z) * sB.x + bhi(w1.z) * sB.y + blo(w1.w) * sB.z + bhi(w1.w) * sB.w;
        a2 += blo(w2.x) * sA.x + bhi(w2.x) * sA.y + blo(w2.y) * sA.z + bhi(w2.y) * sA.w +
              blo(w2.z) * sB.x + bhi(w2.z) * sB.y + blo(w2.w) * sB.z + bhi(w2.w) * sB.w;
        a3 += blo(w3.x) * sA.x + bhi(w3.x) * sA.y + blo(w3.y) * sA.z + bhi(w3.y) * sA.w +
              blo(w3.z) * sB.x + bhi(w3.z) * sB.y + blo(w3.w) * sB.z + bhi(w3.w) * sB.w;
      }
      a0 += __shfl_xor(a0, 1); a0 += __shfl_xor(a0, 2); a0 += __shfl_xor(a0, 4);
      a1 += __shfl_xor(a1, 1); a1 += __shfl_xor(a1, 2); a1 += __shfl_xor(a1, 4);
      a2 += __shfl_xor(a2, 1); a2 += __shfl_xor(a2, 2); a2 += __shfl_xor(a2, 4);
      a3 += __shfl_xor(a3, 1); a3 += __shfl_xor(a3, 2); a3 += __shfl_xor(a3, 4);
      if (hk == 0) {
        int u0 = up * 4, pad = (u0 >> 5);  // rows u0..u0+3 share pad (u0 % 32 <= 28)
        hw2p[u0 + pad] = a0 + b2v0;
        hw2p[u0 + 1 + pad] = a1 + b2v1;
        hw2p[u0 + 2 + pad] = a2 + b2v2;
        hw2p[u0 + 3 + pad] = a3 + b2v3;
      }
    }
    __syncthreads();
    // ---- P2: partial scores over own u-half; 8 threads per region, 32 u each ----
    {
      float s = 0.f;
      int pib = part * 33;
#pragma unroll
      for (int i = 0; i < 4; ++i) {
        uint4 fv = fwreg[i];
        const ushort* fu = (const ushort*)&fv;
        int base = pib + i * 8;
#pragma unroll
        for (int e = 0; e < 8; ++e) {
          float x = bf2f(fu[e]) + hw2p[base + e];
          s += fast_tanh(x) * Vvp[base + e];
        }
      }
      s += __shfl_xor(s, 1); s += __shfl_xor(s, 2); s += __shfl_xor(s, 4);
      if (part == 0) {
        scOwn[lr] = s;
        st_agent(&scG[(size_t)fown * 64 + lr], s);
      }
    }
    __syncthreads();
    // ---- SYNC-A: publish partials, wait partner, softmax (both halves redundantly) ----
    if (tid == 0) {
      __threadfence();
      atomicExch(&flagA[fown], t + 1);
      while (atomicAdd(&flagA[fpar], 0) < t + 1) __builtin_amdgcn_s_sleep(2);
    }
    __syncthreads();
    __threadfence();
    if (tid < 64) {
      float v = scOwn[tid] + ld_agent(&scG[(size_t)fpar * 64 + tid]) + bVr;
      float m = v;
      for (int o = 32; o; o >>= 1) m = fmaxf(m, __shfl_xor(m, o));
      float e = __expf(v - m), ss = e;
      for (int o = 32; o; o >>= 1) ss += __shfl_xor(ss, o);
      attnw[tid] = e / ss;
    }
    __syncthreads();
    // ---- P4: x[j] = sum_l attnw[l]*fkT[j][l] + xE; XOR slot order -> conflict-free ----
    {
      int j = tid;
      float x1 = bf2f(xe1);
#pragma unroll
      for (int s8 = 0; s8 < 8; ++s8) {
        int p = s8 ^ (j & 7);
        uint4 v = *(const uint4*)&fkT[j][p * 8];
        const ushort* vu = (const ushort*)&v;
        const float* aw = &attnw[p * 8];
#pragma unroll
        for (int e = 0; e < 8; ++e) x1 += aw[e] * bf2f(vu[e]);
      }
      xbuf[j] = x1;
      if (tid < 256) {
        int j2 = 512 + tid;
        float x2 = bf2f(xe2);
#pragma unroll
        for (int s8 = 0; s8 < 8; ++s8) {
          int p = s8 ^ (j2 & 7);
          uint4 v = *(const uint4*)&fkT[j2][p * 8];
          const ushort* vu = (const ushort*)&v;
          const float* aw = &attnw[p * 8];
#pragma unroll
          for (int e = 0; e < 8; ++e) x2 += aw[e] * bf2f(vu[e]);
        }
        xbuf[j2] = x2;
      }
    }
    __syncthreads();
    // ---- gates: threads 0..255, unit u = h*256 + tid ----
    if (tid < 256) {
      float xz = xbuf[tid], xr = xbuf[256 + tid], xh = xbuf[512 + tid];
      float z = sigm(xz + g0z + g1z);
      float r = sigm(xr + g0r + g1r);
      float hh = fast_tanh(xh + g0h + r * g1h);
      float st = (1.f - z) * hh;
      int gu = h * 256 + tid;
      stf_p[gu + (gu >> 6) * 4] = st;
      states[((size_t)(t + 1) * 128 + b) * 512 + gu] = f2bf(st);
      st_agent(&stateF[(size_t)((t + 1) & 1) * 65536 + (size_t)b * 512 + gu], st);
    }
    __syncthreads();
    if (tid == 0) {
      __threadfence();
      atomicExch(&flagB[fown], t + 1);
    }
  }
}

extern "C" void kernel_launch(void* const* d_in, const int* in_sizes, int n_in,
                              void* d_out, int out_size, void* d_ws, size_t ws_size,
                              hipStream_t stream) {
  const float* img    = (const float*)d_in[0];
  const int*   target = (const int*)d_in[1];
  const float* W_fc   = (const float*)d_in[2];
  const float* b_fc   = (const float*)d_in[3];
  const float* W1     = (const float*)d_in[4];
  const float* b1     = (const float*)d_in[5];
  const float* W2     = (const float*)d_in[6];
  const float* b2     = (const float*)d_in[7];
  const float* V      = (const float*)d_in[8];
  const float* bV     = (const float*)d_in[9];
  const float* emb    = (const float*)d_in[10];
  const float* gru_k  = (const float*)d_in[11];
  /* d_in[12] = gru_rk: dead (h0 == 0 every step) */
  const float* gru_b  = (const float*)d_in[13];
  const float* fc1_w  = (const float*)d_in[14];
  const float* fc1_b  = (const float*)d_in[15];
  const float* fc2_w  = (const float*)d_in[16];
  const float* fc2_b  = (const float*)d_in[17];

  // ---- d_ws layout (~16 MB): transposed bf16 weights + exchange buffers ----
  char* wsb = (char*)d_ws;
  size_t off = 0;
  auto alloc = [&](size_t bytes) {
    char* p = wsb + off;
    off += (bytes + 255) & ~(size_t)255;
    return p;
  };
  ushort* W_fcT  = (ushort*)alloc((size_t)256 * 2048 * 2);   // 1.05 MB
  ushort* W1T    = (ushort*)alloc((size_t)512 * 256 * 2);    // 0.26 MB
  ushort* W2T    = (ushort*)alloc((size_t)512 * 512 * 2);    // 0.52 MB
  ushort* gruT   = (ushort*)alloc((size_t)1536 * 512 * 2);   // 1.57 MB (row u' = gru_k[:,u'])
  ushort* fc1T   = (ushort*)alloc((size_t)512 * 512 * 2);    // 0.52 MB
  ushort* fc2T   = (ushort*)alloc((size_t)5000 * 512 * 2);   // 5.12 MB
  ushort* hid2ws = (ushort*)alloc((size_t)6016 * 512 * 2);   // 6.16 MB
  float*  stateF = (float*)alloc((size_t)2 * 128 * 512 * 4); // 0.52 MB
  float*  scG    = (float*)alloc((size_t)128 * 2 * 64 * 4);  // 64 KB
  int*    flags  = (int*)alloc((size_t)512 * 4);             // 2 KB (A:0..255, B:256..511)

  // ---- bf16 intermediates inside d_out (120.3 MB; ~65.6 MB used, all dead before
  // the final fc2 GEMM overwrites d_out; fc2 reads only hid2ws/fc2T in d_ws). ----
  char* ob = (char*)d_out;
  ushort* features = (ushort*)(ob);                               // 8192x256   4.19 MB
  ushort* featW1   = (ushort*)(ob + (size_t)4194304);             // 8192x512   8.39 MB
  ushort* states   = (ushort*)(ob + (size_t)12582912);            // 48x128x512 6.29 MB
  ushort* embA     = (ushort*)(ob + (size_t)18874368);            // 6016x256   3.08 MB
  ushort* featK    = (ushort*)(ob + (size_t)21954560);            // 8192x1536 25.17 MB
  ushort* xE       = (ushort*)(ob + (size_t)47120384);            // 6016x1536 18.48 MB

  dim3 tb(32, 8);
  transpose_f2b<<<dim3(8, 64), tb, 0, stream>>>(W_fc, W_fcT, 2048, 256);
  transpose_f2b<<<dim3(16, 8), tb, 0, stream>>>(W1, W1T, 256, 512);
  transpose_f2b<<<dim3(16, 16), tb, 0, stream>>>(W2, W2T, 512, 512);
  transpose_f2b<<<dim3(48, 16), tb, 0, stream>>>(gru_k, gruT, 512, 1536);
  transpose_f2b<<<dim3(16, 16), tb, 0, stream>>>(fc1_w, fc1T, 512, 512);
  transpose_f2b<<<dim3(157, 16), tb, 0, stream>>>(fc2_w, fc2T, 512, 5000);

  embed_gather<<<6016, 256, 0, stream>>>(target, emb, embA);

  // encoder: features = relu(img @ W_fc + b_fc)   (8192,256) K=2048, fp32 A
  gemm128<<<dim3(2, 64), 256, 0, stream>>>(img, W_fcT, b_fc, features,
                                           8192, 256, 2048, 256, 2048, 1 | 8);
  // featW1 = features @ W1 + b1                   (8192,512) K=256
  gemm128<<<dim3(4, 64), 256, 0, stream>>>(features, W1T, b1, featW1,
                                           8192, 512, 256, 512, 256, 0);
  // featK = features @ gru_k[0:256,:]             (8192,1536) K=256
  gemm128<<<dim3(12, 64), 256, 0, stream>>>(features, gruT, nullptr, featK,
                                            8192, 1536, 256, 1536, 512, 0);
  // xE = embA @ gru_k[256:512,:]                  (6016,1536) K=256
  gemm128<<<dim3(12, 47), 256, 0, stream>>>(embA, gruT + 256, nullptr, xE,
                                            6016, 1536, 256, 1536, 512, 0);

  // reset pair-sync flags (graph replays reuse d_ws)
  hipMemsetAsync(flags, 0, 512 * sizeof(int), stream);

  // persistent pair recurrence: 256 blocks (1/CU), cooperative for co-residency
  {
    const ushort *a0 = featW1, *a1 = W2T, *a5 = featK, *a6 = xE;
    const float *a2 = b2, *a3 = V, *a4 = bV, *a7 = gru_b, *a8 = gru_b + 1536;
    ushort* a9 = states;
    float *a10 = stateF, *a11 = scG;
    int *a12 = flags, *a13 = flags + 256;
    void* kargs[] = {&a0, &a1, &a2, &a3, &a4, &a5, &a6, &a7, &a8, &a9, &a10, &a11, &a12, &a13};
    hipLaunchCooperativeKernel((void*)row_pair, dim3(256), dim3(512), kargs, 0, stream);
  }

  // fc1 over all steps: (6016,512) K=512
  gemm128<<<dim3(4, 47), 256, 0, stream>>>(states + (size_t)128 * 512, fc1T, fc1_b,
                                           hid2ws, 6016, 512, 512, 512, 512, 0);
  // fc2 -> d_out fp32 with (t,b)->(b,t) remap: (6016,5000) K=512
  gemm128<<<dim3(40, 47), 256, 0, stream>>>(hid2ws, fc2T, fc2_b, d_out,
                                            6016, 5000, 512, 5000, 512, 2 | 4);
}